// Round 1
// 466.504 us; speedup vs baseline: 1.1261x; 1.1261x over previous
//
#include <hip/hip_runtime.h>
#include <hip/hip_bf16.h>

using bf16 = __hip_bfloat16;
using floatx4 = __attribute__((ext_vector_type(4))) float;
using bf16x8  = __attribute__((ext_vector_type(8))) __bf16;
using bf16x2  = __attribute__((ext_vector_type(2))) __bf16;

#define MDIM 8192   // B*T
#define NDIM 2048   // C
#define KDIM 2048   // C
#define TSEQ 2048   // T
#define BB   4      // batch
#define CDIM 2048   // C
#define NCHUNK 64
#define TCHUNK 32   // TSEQ/NCHUNK

typedef __attribute__((address_space(1))) void gvoid_t;
typedef __attribute__((address_space(3))) void lvoid_t;

__device__ __forceinline__ void load_lds16(const void* g, void* l) {
  __builtin_amdgcn_global_load_lds((gvoid_t*)(void*)g, (lvoid_t*)l, 16, 0, 0);
}

// ---------------- fp32 -> bf16 convert: all 5 matrices, one launch ------------
__global__ __launch_bounds__(256) void cvt_all(
    const float* __restrict__ x,
    const float* __restrict__ Wk, const float* __restrict__ Wv,
    const float* __restrict__ Wr, const float* __restrict__ Wo,
    __bf16* __restrict__ xb,
    __bf16* __restrict__ wkb, __bf16* __restrict__ wvb,
    __bf16* __restrict__ wrb, __bf16* __restrict__ wob) {
  const size_t WN = (size_t)NDIM * KDIM;
  const int slice = blockIdx.y;
  const float* s;
  __bf16* d;
  if (slice < 4) { s = x + (size_t)slice * WN; d = xb + (size_t)slice * WN; }
  else {
    s = (slice == 4) ? Wk : (slice == 5) ? Wv : (slice == 6) ? Wr : Wo;
    d = (slice == 4) ? wkb : (slice == 5) ? wvb : (slice == 6) ? wrb : wob;
  }
  const int i = (blockIdx.x * 256 + threadIdx.x) * 8;
  float4 a = *(const float4*)(s + i);
  float4 b = *(const float4*)(s + i + 4);
  bf16x8 o;
  o[0] = (__bf16)a.x; o[1] = (__bf16)a.y; o[2] = (__bf16)a.z; o[3] = (__bf16)a.w;
  o[4] = (__bf16)b.x; o[5] = (__bf16)b.y; o[6] = (__bf16)b.z; o[7] = (__bf16)b.w;
  *(bf16x8*)(d + i) = o;
}

// ---------------- GEMM: C[m,n] = sum_k A[m,k] * B[n,k], bf16 in, fp32 acc -----
// 256x256 tile, BK=64, 512 threads = 8 waves (2 M x 4 N), each wave owns
// a 128x64 output = 8x4 frags of 16x16.  8-phase-per-2-tiles schedule
// (4 phases/tile: (kk, n-half)), counted vmcnt(4) (never 0 in loop),
// double-buffered 128 KiB LDS, setprio(1) around each 16-MFMA cluster.
//
// LDS layout per matrix per buffer (32 KiB): region (kk, rh) of 8 KiB holds
// rows [rh*128, rh*128+128) x K-cols [kk*32, kk*32+32).  Within a region,
// row r' (64 B) has four 16-B slots; slot sc holds data chunk sc ^ ((r'>>1)&3)
// (XOR swizzle -> ds_read_b128 frag reads are bank-uniform: 8 lanes / 16-B
// slot).  global_load_lds dest stays LINEAR (base + tid*16); the swizzle is
// applied to the per-lane GLOBAL source address (both-sides-or-neither).
//
// Per-tile staging = 8 loads/thread, issue order A-k0 x2, B-k0 x2, A-k1 x2,
// B-k1 x2 (2 per phase) into the buffer freed at the last tile boundary.
// vmcnt(4) before the trailing barrier of phases 2 and 4:
//   P2: newest 4 outstanding = next-tile K0  => this tile's K1 landed.
//   P4: newest 4 outstanding = next-tile K1  => next tile's K0 landed.
// Barriers are raw s_barrier via asm with "memory" clobber (no vmcnt drain,
// but a compiler reorder fence so reads can't hoist past the cross-wave
// guarantee point).

#define GBARRIER() asm volatile("s_barrier" ::: "memory")
#define VMW4()     asm volatile("s_waitcnt vmcnt(4)" ::: "memory")
#define VMW0()     asm volatile("s_waitcnt vmcnt(0)" ::: "memory")

template <typename CT>
__device__ __forceinline__ void gemm256_body(const __bf16* __restrict__ A,
                                             const __bf16* __restrict__ B,
                                             CT* __restrict__ C,
                                             const int bm, const int bn) {
  __shared__ __attribute__((aligned(128))) unsigned char lds[131072];
  const int tid  = threadIdx.x;
  const int lane = tid & 63;
  const int wave = tid >> 6;
  const int wm = wave >> 2;   // 0..1
  const int wn = wave & 3;    // 0..3

  floatx4 acc[8][4] = {};
  bf16x8 af[8], bfr[2];

  // staging: thread tid covers row (tid>>2) of a 128-row region, 16 B at
  // swizzled chunk ((tid&3) ^ ((tid>>3)&3))  [(row'>>1)&3 == (tid>>3)&3]
  const int srow = tid >> 2;
  const int scol = ((tid & 3) ^ ((tid >> 3) & 3)) * 8;
  const __bf16* Ag = A + (size_t)(bm * 256 + srow) * KDIM + scol;
  const __bf16* Bg = B + (size_t)(bn * 256 + srow) * KDIM + scol;
  const uint32_t sdst = (uint32_t)tid * 16u;

  // frag-read lane offset: row (lane&15), slot (lane>>4) ^ ((lane>>1)&3)
  const uint32_t laneoff =
      (uint32_t)((lane & 15) * 64 + (((lane >> 4) ^ ((lane >> 1) & 3)) * 16));
  const uint32_t aoff = (uint32_t)(wm * 8192) + laneoff;
  const uint32_t boff = 65536u +
      (uint32_t)((wn >> 1) * 8192 + (wn & 1) * 4096) + laneoff;

#define STG_A(bf_, kt_, kk_, rh_)                                             \
  load_lds16(Ag + (size_t)(rh_) * 128 * KDIM + (size_t)((kt_) * 64 + (kk_) * 32), \
             (void*)(lds + (bf_) + (kk_) * 16384u + (rh_) * 8192u + sdst))
#define STG_B(bf_, kt_, kk_, rh_)                                             \
  load_lds16(Bg + (size_t)(rh_) * 128 * KDIM + (size_t)((kt_) * 64 + (kk_) * 32), \
             (void*)(lds + 65536u + (bf_) + (kk_) * 16384u + (rh_) * 8192u + sdst))
#define RD_A(kk_, bo_) {                                                      \
  const uint32_t ab = (bo_) + (kk_) * 16384u + aoff;                          \
  af[0] = *(const bf16x8*)(lds + ab);        af[1] = *(const bf16x8*)(lds + ab + 1024); \
  af[2] = *(const bf16x8*)(lds + ab + 2048); af[3] = *(const bf16x8*)(lds + ab + 3072); \
  af[4] = *(const bf16x8*)(lds + ab + 4096); af[5] = *(const bf16x8*)(lds + ab + 5120); \
  af[6] = *(const bf16x8*)(lds + ab + 6144); af[7] = *(const bf16x8*)(lds + ab + 7168); }
#define RD_B(kk_, n0_, bo_) {                                                 \
  const uint32_t bb = (bo_) + (kk_) * 16384u + boff + (n0_) * 1024u;          \
  bfr[0] = *(const bf16x8*)(lds + bb);                                        \
  bfr[1] = *(const bf16x8*)(lds + bb + 1024); }
#define MFMA8(j0_, j1_) {                                                     \
  __builtin_amdgcn_s_setprio(1);                                              \
  _Pragma("unroll")                                                           \
  for (int m_ = 0; m_ < 8; ++m_) {                                            \
    acc[m_][j0_] = __builtin_amdgcn_mfma_f32_16x16x32_bf16(af[m_], bfr[0], acc[m_][j0_], 0, 0, 0); \
    acc[m_][j1_] = __builtin_amdgcn_mfma_f32_16x16x32_bf16(af[m_], bfr[1], acc[m_][j1_], 0, 0, 0); \
  }                                                                           \
  __builtin_amdgcn_s_setprio(0); }

  // ---- prologue: stage tile 0 into buf0 (order: A-k0, B-k0, A-k1, B-k1)
  STG_A(0u, 0, 0, 0); STG_A(0u, 0, 0, 1);
  STG_B(0u, 0, 0, 0); STG_B(0u, 0, 0, 1);
  STG_A(0u, 0, 1, 0); STG_A(0u, 0, 1, 1);
  STG_B(0u, 0, 1, 0); STG_B(0u, 0, 1, 1);
  VMW4();        // K0 of tile 0 landed (K1's 4 loads may stay in flight)
  GBARRIER();

  constexpr int NT = KDIM / 64;   // 32
  for (int t = 0; t < NT - 1; ++t) {
    const uint32_t bo  = (uint32_t)(t & 1) * 32768u;
    const uint32_t bo1 = bo ^ 32768u;
    // P1: kk=0, n-half 0 ; stage next-tile A-k0
    RD_A(0, bo); RD_B(0, 0, bo);
    STG_A(bo1, t + 1, 0, 0); STG_A(bo1, t + 1, 0, 1);
    GBARRIER();
    MFMA8(0, 1);
    GBARRIER();
    // P2: kk=0, n-half 1 ; stage next-tile B-k0 ; prove this tile's K1
    RD_B(0, 2, bo);
    STG_B(bo1, t + 1, 0, 0); STG_B(bo1, t + 1, 0, 1);
    VMW4();
    GBARRIER();
    MFMA8(2, 3);
    GBARRIER();
    // P3: kk=1, n-half 0 ; stage next-tile A-k1
    RD_A(1, bo); RD_B(1, 0, bo);
    STG_A(bo1, t + 1, 1, 0); STG_A(bo1, t + 1, 1, 1);
    GBARRIER();
    MFMA8(0, 1);
    GBARRIER();
    // P4: kk=1, n-half 1 ; stage next-tile B-k1 ; prove next tile's K0
    RD_B(1, 2, bo);
    STG_B(bo1, t + 1, 1, 0); STG_B(bo1, t + 1, 1, 1);
    VMW4();
    GBARRIER();
    MFMA8(2, 3);
    GBARRIER();
  }
  { // ---- epilogue tile NT-1: no staging; drain at P2
    const uint32_t bo = (uint32_t)((NT - 1) & 1) * 32768u;
    RD_A(0, bo); RD_B(0, 0, bo);
    GBARRIER();
    MFMA8(0, 1);
    GBARRIER();
    RD_B(0, 2, bo);
    VMW0();
    GBARRIER();
    MFMA8(2, 3);
    GBARRIER();
    RD_A(1, bo); RD_B(1, 0, bo);
    MFMA8(0, 1);
    RD_B(1, 2, bo);
    MFMA8(2, 3);
  }

  // C/D layout: col = lane&15, row = (lane>>4)*4 + reg
  const int crow = (lane >> 4) * 4;
  const int ccol = lane & 15;
#pragma unroll
  for (int i = 0; i < 8; ++i)
#pragma unroll
    for (int j = 0; j < 4; ++j) {
      const size_t r0 = (size_t)(bm * 256 + wm * 128 + i * 16 + crow);
      const int    c0 = bn * 256 + wn * 64 + j * 16 + ccol;
#pragma unroll
      for (int rg = 0; rg < 4; ++rg)
        C[(r0 + rg) * NDIM + c0] = (CT)(acc[i][j][rg]);
    }
#undef STG_A
#undef STG_B
#undef RD_A
#undef RD_B
#undef MFMA8
}

// XCD-aware bijective swizzle over the 256 blocks of one z-slice: each XCD
// owns one bn column -> its 1 MB B-panel is L2-resident.
__device__ __forceinline__ void xcd_swz(int& bm, int& bn) {
  const int f = (int)(blockIdx.y * 32 + blockIdx.x);   // 0..255
  const int s = (f & 7) * 32 + (f >> 3);
  bm = s & 31;
  bn = s >> 5;
}

__global__ __launch_bounds__(512, 2) void gemm_qkv(const __bf16* __restrict__ x,
                                                   const __bf16* __restrict__ Wk,
                                                   const __bf16* __restrict__ Wv,
                                                   const __bf16* __restrict__ Wr,
                                                   __bf16* __restrict__ kb,
                                                   __bf16* __restrict__ vb,
                                                   __bf16* __restrict__ rb) {
  const __bf16* Bsel = (blockIdx.z == 0) ? Wk : (blockIdx.z == 1) ? Wv : Wr;
  __bf16*       Csel = (blockIdx.z == 0) ? kb : (blockIdx.z == 1) ? vb : rb;
  int bm, bn; xcd_swz(bm, bn);
  gemm256_body<__bf16>(x, Bsel, Csel, bm, bn);
}

__global__ __launch_bounds__(512, 2) void gemm_o(const __bf16* __restrict__ A,
                                                 const __bf16* __restrict__ B,
                                                 float* __restrict__ C) {
  int bm, bn; xcd_swz(bm, bn);
  gemm256_body<float>(A, B, C, bm, bn);
}

// ---------------- WKV blocked scan (3-phase), 2 channels/thread ----------------
__global__ __launch_bounds__(256) void wkv_summary(
    const __bf16* __restrict__ kb, const __bf16* __restrict__ vb,
    const float* __restrict__ td, const float* __restrict__ tf,
    float* __restrict__ nsum, float* __restrict__ dsum) {
  const int c0 = (blockIdx.x * 256 + threadIdx.x) * 2;
  const int chunk = blockIdx.y;
  const int b = blockIdx.z;
  const float dc0 = __expf(-__expf(td[c0]));
  const float dc1 = __expf(-__expf(td[c0 + 1]));
  const float fi0 = __expf(tf[c0]);
  const float fi1 = __expf(tf[c0 + 1]);
  size_t base = ((size_t)b * TSEQ + (size_t)chunk * TCHUNK) * CDIM + c0;
  float n0 = 0.f, d0 = 0.f, n1 = 0.f, d1 = 0.f;
#pragma unroll 4
  for (int t = 0; t < TCHUNK; ++t) {
    bf16x2 k2 = *(const bf16x2*)(kb + base + (size_t)t * CDIM);
    bf16x2 v2 = *(const bf16x2*)(vb + base + (size_t)t * CDIM);
    float k0f = fminf(fmaxf((float)k2[0], -10.f), 10.f);
    float k1f = fminf(fmaxf((float)k2[1], -10.f), 10.f);
    float w0 = __expf(k0f), w1 = __expf(k1f);
    if (chunk == 0 && t == 0) { w0 *= fi0; w1 *= fi1; }
    n0 = dc0 * n0 + w0 * (float)v2[0];
    d0 = dc0 * d0 + w0;
    n1 = dc1 * n1 + w1 * (float)v2[1];
    d1 = dc1 * d1 + w1;
  }
  const size_t si = (size_t)(chunk * BB + b) * CDIM + c0;
  *(float2*)(nsum + si) = make_float2(n0, n1);
  *(float2*)(dsum + si) = make_float2(d0, d1);
}

__global__ __launch_bounds__(256) void wkv_scan(
    const float* __restrict__ td,
    float* __restrict__ nsum, float* __restrict__ dsum) {
  const int c0 = (blockIdx.x * 256 + threadIdx.x) * 2;
  const int b = blockIdx.y;
  const float dT0 = __expf(-__expf(td[c0]) * (float)TCHUNK);
  const float dT1 = __expf(-__expf(td[c0 + 1]) * (float)TCHUNK);
  float pn0 = 0.f, pd0 = 0.f, pn1 = 0.f, pd1 = 0.f;
  for (int j = 0; j < NCHUNK; ++j) {
    const size_t si = (size_t)(j * BB + b) * CDIM + c0;
    float2 Sn = *(const float2*)(nsum + si);
    float2 Sd = *(const float2*)(dsum + si);
    *(float2*)(nsum + si) = make_float2(pn0, pn1);
    *(float2*)(dsum + si) = make_float2(pd0, pd1);
    pn0 = dT0 * pn0 + Sn.x;  pn1 = dT1 * pn1 + Sn.y;
    pd0 = dT0 * pd0 + Sd.x;  pd1 = dT1 * pd1 + Sd.y;
  }
}

__global__ __launch_bounds__(256) void wkv_apply(
    const __bf16* __restrict__ kb, const __bf16* __restrict__ vb,
    __bf16* __restrict__ rb,
    const float* __restrict__ td, const float* __restrict__ tf,
    const float* __restrict__ nsum, const float* __restrict__ dsum) {
  const int c0 = (blockIdx.x * 256 + threadIdx.x) * 2;
  const int chunk = blockIdx.y;
  const int b = blockIdx.z;
  const float dc0 = __expf(-__expf(td[c0]));
  const float dc1 = __expf(-__expf(td[c0 + 1]));
  const float fi0 = __expf(tf[c0]);
  const float fi1 = __expf(tf[c0 + 1]);

  const size_t si = (size_t)(chunk * BB + b) * CDIM + c0;
  float2 pn = *(const float2*)(nsum + si);
  float2 pd = *(const float2*)(dsum + si);
  float n0 = pn.x, n1 = pn.y, d0 = pd.x, d1 = pd.y;

  size_t base = ((size_t)b * TSEQ + (size_t)chunk * TCHUNK) * CDIM + c0;
#pragma unroll 2
  for (int t = 0; t < TCHUNK; ++t) {
    const size_t idx = base + (size_t)t * CDIM;
    bf16x2 k2 = *(const bf16x2*)(kb + idx);
    bf16x2 v2 = *(const bf16x2*)(vb + idx);
    bf16x2 r2 = *(const bf16x2*)(rb + idx);
    float k0f = fminf(fmaxf((float)k2[0], -10.f), 10.f);
    float k1f = fminf(fmaxf((float)k2[1], -10.f), 10.f);
    float w0 = __expf(k0f), w1 = __expf(k1f);
    if (chunk == 0 && t == 0) { w0 *= fi0; w1 *= fi1; }
    n0 = dc0 * n0 + w0 * (float)v2[0];
    d0 = dc0 * d0 + w0;
    n1 = dc1 * n1 + w1 * (float)v2[1];
    d1 = dc1 * d1 + w1;
    const float wkv0 = n0 * __builtin_amdgcn_rcpf(d0 + 1e-6f);
    const float wkv1 = n1 * __builtin_amdgcn_rcpf(d1 + 1e-6f);
    const float sr0 = __builtin_amdgcn_rcpf(1.f + __expf(-(float)r2[0]));
    const float sr1 = __builtin_amdgcn_rcpf(1.f + __expf(-(float)r2[1]));
    bf16x2 o;
    o[0] = (__bf16)(sr0 * wkv0);
    o[1] = (__bf16)(sr1 * wkv1);
    *(bf16x2*)(rb + idx) = o;
  }
}

// ---------------- launch -------------------------------------------------------
extern "C" void kernel_launch(void* const* d_in, const int* in_sizes, int n_in,
                              void* d_out, int out_size, void* d_ws, size_t ws_size,
                              hipStream_t stream) {
  const float* x  = (const float*)d_in[0];
  const float* Wk = (const float*)d_in[1];
  const float* Wv = (const float*)d_in[2];
  const float* Wr = (const float*)d_in[3];
  const float* Wo = (const float*)d_in[4];
  const float* td = (const float*)d_in[5];
  const float* tf = (const float*)d_in[6];
  float* out = (float*)d_out;

  char* ws = (char*)d_ws;
  const size_t matX = (size_t)MDIM * KDIM * sizeof(__bf16);  // 33.5 MB
  const size_t matW = (size_t)NDIM * KDIM * sizeof(__bf16);  // 8.4 MB
  __bf16* xb  = (__bf16*)(ws);
  __bf16* wkb = (__bf16*)(ws + matX);
  __bf16* wvb = (__bf16*)(ws + matX + matW);
  __bf16* wrb = (__bf16*)(ws + matX + 2 * matW);
  __bf16* wob = (__bf16*)(ws + matX + 3 * matW);
  __bf16* kb  = (__bf16*)(ws + matX + 4 * matW);
  __bf16* vb  = (__bf16*)(ws + 2 * matX + 4 * matW);
  __bf16* rb  = (__bf16*)(ws + 3 * matX + 4 * matW);
  float* nsum = (float*)(ws + 4 * matX + 4 * matW);
  float* dsum = nsum + (size_t)NCHUNK * BB * CDIM;

  dim3 blk(256);
  dim3 blk5(512);
  cvt_all<<<dim3(NDIM * KDIM / (8 * 256), 8), blk, 0, stream>>>(
      x, Wk, Wv, Wr, Wo, xb, wkb, wvb, wrb, wob);

  dim3 gq(MDIM / 256, NDIM / 256, 3);
  gemm_qkv<<<gq, blk5, 0, stream>>>(xb, wkb, wvb, wrb, kb, vb, rb);
  dim3 gw(CDIM / 512, NCHUNK, BB);
  wkv_summary<<<gw, blk, 0, stream>>>(kb, vb, td, tf, nsum, dsum);
  wkv_scan<<<dim3(CDIM / 512, BB), blk, 0, stream>>>(td, nsum, dsum);
  wkv_apply<<<gw, blk, 0, stream>>>(kb, vb, rb, td, tf, nsum, dsum);
  dim3 go(MDIM / 256, NDIM / 256, 1);
  gemm_o<<<go, blk5, 0, stream>>>(rb, wob, out);
}